// Round 15
// baseline (334.824 us; speedup 1.0000x reference)
//
#include <hip/hip_runtime.h>
#include <cfloat>
#include <cstdint>

#define B_   8
#define N_   1024
#define H_   128
#define K_   20
#define EPS_ 1e-6f
#define R_   (B_ * 3 * N_)

typedef _Float16 half_t;
typedef _Float16 h8_t __attribute__((ext_vector_type(8)));
typedef _Float16 h4_t __attribute__((ext_vector_type(4)));
typedef __attribute__((ext_vector_type(4))) float f4_t;

__device__ inline void st4h(half_t* __restrict__ p, size_t off, f4_t v) {
    h4_t o;
    o[0] = (half_t)v[0]; o[1] = (half_t)v[1]; o[2] = (half_t)v[2]; o[3] = (half_t)v[3];
    *(h4_t*)(p + off) = o;
}

#define OFF_FC 0
#define OFF_D0 32768
#define OFF_W0 294912
#define OFF_D1 425984
#define OFF_W1 491520
#define OFF_WS 557056
#define W_TOT  688128

// ---------------------------------------------------------------------------
// Fused: weight fp32->fp16 convert (grid-stride prologue) + kNN selection +
// Gram-algebra VN conv. Per wave: one query; winners in LDS; conv uses
// exact identities E.R=0, C.R=0 to reduce per-(k,ch) work ~3x.
// ---------------------------------------------------------------------------
__global__ __launch_bounds__(256) void knn_conv(const float* __restrict__ x,
                                                const float* __restrict__ Wf,
                                                const float* __restrict__ Wd,
                                                const float* __restrict__ Wfc,
                                                const float* __restrict__ Wd0,
                                                const float* __restrict__ W0,
                                                const float* __restrict__ Wd1,
                                                const float* __restrict__ W1,
                                                const float* __restrict__ Wsc,
                                                half_t* __restrict__ wAll,
                                                half_t* __restrict__ h1) {
    int t = threadIdx.x;
    // ---- weight conversion (grid-stride; 2048 blocks x 256 thr x 2 iters) ----
    for (int i = blockIdx.x * 256 + t; i < W_TOT; i += 2048 * 256) {
        const float* src; int off;
        if (i < OFF_W0)      { if (i < OFF_D0) { src = Wfc; off = OFF_FC; }
                               else            { src = Wd0; off = OFF_D0; } }
        else if (i < OFF_W1) { if (i < OFF_D1) { src = W0;  off = OFF_W0; }
                               else            { src = Wd1; off = OFF_D1; } }
        else                 { if (i < OFF_WS) { src = W1;  off = OFF_W1; }
                               else            { src = Wsc; off = OFF_WS; } }
        wAll[i] = (half_t)src[i - off];
    }

    __shared__ float xs[N_], ys[N_], zs[N_];
    __shared__ int opw[4][K_];
    int wv = t >> 6, lane = t & 63;
    int b = blockIdx.x >> 8;
    int n = (blockIdx.x & 255) * 4 + wv;
    const float* xb = x + (size_t)b * N_ * 3;
    for (int j = t; j < N_; j += 256) {
        xs[j] = xb[j * 3 + 0];
        ys[j] = xb[j * 3 + 1];
        zs[j] = xb[j * 3 + 2];
    }
    __syncthreads();

    float cx = xs[n], cy = ys[n], cz = zs[n];
    uint ku[16];
    #pragma unroll
    for (int k = 0; k < 16; ++k) {
        int j = lane + (k << 6);
        float dx = xs[j] - cx, dy = ys[j] - cy, dz = zs[j] - cz;
        float d = dx * dx + dy * dy + dz * dz;
        ku[k] = (__float_as_uint(d) & 0xFFFFFC00u) | (uint)j;
    }
    for (int s = 0; s < K_; ++s) {
        uint m = ku[0];
        #pragma unroll
        for (int k = 1; k < 16; ++k) m = min(m, ku[k]);
        #pragma unroll
        for (int o = 32; o; o >>= 1) m = min(m, (uint)__shfl_xor((int)m, o));
        int j = (int)(m & 1023u);
        if ((j & 63) == lane) {
            opw[wv][s] = j;
            ku[j >> 6] = 0xFFFFFFFFu;
        }
    }
    __syncthreads();

    // ---- Gram-algebra conv for channels lane, lane+64 ----
    float wf[2][3], wd[2][3];
    float a1[2], a2[2], a3[2], a4[2], b1[2], b2[2], b3[2], b4[2];
    #pragma unroll
    for (int c = 0; c < 2; ++c) {
        int ch = lane + c * 64;
        wf[c][0] = Wf[ch * 3 + 0]; wf[c][1] = Wf[ch * 3 + 1]; wf[c][2] = Wf[ch * 3 + 2];
        wd[c][0] = Wd[ch * 3 + 0]; wd[c][1] = Wd[ch * 3 + 1]; wd[c][2] = Wd[ch * 3 + 2];
        a1[c] = wf[c][0] * wd[c][0];
        a2[c] = wf[c][0] * wd[c][1] + wf[c][1] * wd[c][0];
        a3[c] = wf[c][1] * wd[c][1];
        a4[c] = wf[c][2] * wd[c][2];
        b1[c] = wd[c][0] * wd[c][0];
        b2[c] = 2.f * wd[c][0] * wd[c][1];
        b3[c] = wd[c][1] * wd[c][1];
        b4[c] = wd[c][2] * wd[c][2];
    }
    const float Gcc = cx * cx + cy * cy + cz * cz;
    float SE[3] = {0.f, 0.f, 0.f}, SR[3] = {0.f, 0.f, 0.f};
    float SB[2] = {0.f, 0.f};
    float SBE[2][3] = {}, SBR[2][3] = {};

    for (int k = 0; k < K_; ++k) {
        int j = opw[wv][k];
        float nx = xs[j], ny = ys[j], nz = zs[j];
        float ex = nx - cx, ey = ny - cy, ez = nz - cz;
        float rx = ny * cz - nz * cy;
        float ry = nz * cx - nx * cz;
        float rz = nx * cy - ny * cx;
        float Gee = ex * ex + ey * ey + ez * ez;
        float Gec = ex * cx + ey * cy + ez * cz;
        float Grr = rx * rx + ry * ry + rz * rz;
        SE[0] += ex; SE[1] += ey; SE[2] += ez;
        SR[0] += rx; SR[1] += ry; SR[2] += rz;
        #pragma unroll
        for (int c = 0; c < 2; ++c) {
            float dot = a1[c] * Gee + a2[c] * Gec + a3[c] * Gcc + a4[c] * Grr;
            float dsq = EPS_ + b1[c] * Gee + b2[c] * Gec + b3[c] * Gcc + b4[c] * Grr;
            float cf = dot * __builtin_amdgcn_rcpf(dsq);
            float B = (dot >= 0.f) ? 0.f : (-0.8f * cf);
            SB[c] += B;
            SBE[c][0] += B * ex; SBE[c][1] += B * ey; SBE[c][2] += B * ez;
            SBR[c][0] += B * rx; SBR[c][1] += B * ry; SBR[c][2] += B * rz;
        }
    }
    const float inv = 1.0f / (float)K_;
    const float Kf = (float)K_;
    size_t r0 = ((size_t)b * 3) * N_ + n;
    float ctr[3] = {cx, cy, cz};
    #pragma unroll
    for (int c = 0; c < 2; ++c) {
        int ch = lane + c * 64;
        #pragma unroll
        for (int v = 0; v < 3; ++v) {
            float o = wf[c][0] * SE[v] + wf[c][1] * (Kf * ctr[v]) + wf[c][2] * SR[v]
                    + wd[c][0] * SBE[c][v] + wd[c][1] * (SB[c] * ctr[v]) + wd[c][2] * SBR[c][v];
            h1[(r0 + (size_t)v * N_) * H_ + ch] = (half_t)(o * inv);
        }
    }
}

// ---------------------------------------------------------------------------
// Swizzled LDS helpers (128/256-ch row buffers).
// ---------------------------------------------------------------------------
__device__ inline void stsw128(half_t* __restrict__ buf, int v, int n, int o, f4_t val) {
    int phys = (((o >> 3) ^ (n & 7)) * 8) + (o & 7);
    half_t* p = buf + (v * 16 + n) * 128 + phys;
    h4_t h;
    h[0] = (half_t)val[0]; h[1] = (half_t)val[1];
    h[2] = (half_t)val[2]; h[3] = (half_t)val[3];
    *(h4_t*)p = h;
}
__device__ inline f4_t ldsw128(const half_t* __restrict__ buf, int v, int n, int o) {
    int phys = (((o >> 3) ^ (n & 7)) * 8) + (o & 7);
    const half_t* p = buf + (v * 16 + n) * 128 + phys;
    h4_t x = *(const h4_t*)p;
    f4_t r;
    r[0] = (float)x[0]; r[1] = (float)x[1]; r[2] = (float)x[2]; r[3] = (float)x[3];
    return r;
}
__device__ inline void stsw256(half_t* __restrict__ buf, int v, int n, int o, f4_t val) {
    int phys = (((o >> 3) ^ (n & 7)) * 8) + (o & 7);
    half_t* p = buf + (v * 16 + n) * 256 + phys;
    h4_t h;
    h[0] = (half_t)val[0]; h[1] = (half_t)val[1];
    h[2] = (half_t)val[2]; h[3] = (half_t)val[3];
    *(h4_t*)p = h;
}
__device__ inline f4_t ldsw256(const half_t* __restrict__ buf, int v, int n, int o) {
    int phys = (((o >> 3) ^ (n & 7)) * 8) + (o & 7);
    const half_t* p = buf + (v * 16 + n) * 256 + phys;
    h4_t x = *(const h4_t*)p;
    f4_t r;
    r[0] = (float)x[0]; r[1] = (float)x[1]; r[2] = (float)x[2]; r[3] = (float)x[3];
    return r;
}

// ---------------------------------------------------------------------------
// block_full: entire resnet block per (n-tile 16, b) block (R13/R14 design).
// ---------------------------------------------------------------------------
template<bool FIRST, bool WRITE_OUT>
__global__ __launch_bounds__(256) void block_full(const half_t* __restrict__ Wfc,
                                                  const half_t* __restrict__ Wd0,
                                                  const half_t* __restrict__ W0,
                                                  const half_t* __restrict__ Wd1,
                                                  const half_t* __restrict__ Ws,
                                                  const half_t* __restrict__ W1,
                                                  const half_t* __restrict__ hprev,
                                                  const float* __restrict__ P,
                                                  const float* __restrict__ addD0,
                                                  const float* __restrict__ addWs,
                                                  half_t* __restrict__ outH,
                                                  float* __restrict__ Pp) {
    __shared__ __align__(16) char smem[FIRST ? 77824 : 53248];
    half_t* hL   = (half_t*)(smem);
    half_t* netL = (half_t*)(FIRST ? smem : smem + 36864);
    half_t* HdL  = (half_t*)(smem + 12288);
    half_t* a0L  = (half_t*)(FIRST ? smem + 36864 : smem + 12288);
    half_t* a1L  = (half_t*)(FIRST ? smem + 36864 : smem + 24576);
    half_t* AsA  = (half_t*)(FIRST ? smem + 61440 : smem + 36864);
    half_t* AsB  = (half_t*)(FIRST ? smem + 61440 : smem + 12288);

    const int t = threadIdx.x;
    const int lane = t & 63, wm = t >> 6;
    const int l16 = lane & 15, quad = lane >> 4;
    const int sw = (quad ^ (l16 & 3)) * 8;
    const int b  = blockIdx.z;
    const int nt = blockIdx.x;
    const int n0 = nt * 16;
    const size_t row0 = (size_t)(b * 3) * N_ + (n0 + l16);

    #pragma unroll
    for (int c = t; c < 768; c += 256) {
        int v = c >> 8, rem = c & 255;
        int n = rem >> 4, ch = rem & 15;
        size_t g = (size_t)((b * 3 + v) * N_ + n0 + n) * 128 + ch * 8;
        *(uint4*)(hL + (v * 16 + n) * 128 + ((ch ^ (n & 7)) * 8)) =
            *(const uint4*)(hprev + g);
    }

    if (FIRST) {
        f4_t facc[3][4];
        #pragma unroll
        for (int v = 0; v < 3; ++v)
            #pragma unroll
            for (int i = 0; i < 4; ++i)
                #pragma unroll
                for (int e = 0; e < 4; ++e) facc[v][i][e] = 0.f;
        for (int k0 = 0; k0 < 128; k0 += 32) {
            #pragma unroll
            for (int c = t; c < 1024; c += 256) {
                int row = c >> 2, ch = c & 3;
                size_t g = (size_t)row * 128 + k0 + ch * 8;
                *(uint4*)(AsA + row * 32 + ((ch ^ (row & 3)) * 8)) =
                    *(const uint4*)(Wfc + g);
            }
            __syncthreads();
            h8_t ah[4], bh[3];
            #pragma unroll
            for (int i = 0; i < 4; ++i)
                ah[i] = *(const h8_t*)(AsA + (wm * 64 + i * 16 + l16) * 32 + sw);
            int lc = (k0 >> 3) + quad;
            #pragma unroll
            for (int v = 0; v < 3; ++v)
                bh[v] = *(const h8_t*)(hL + (v * 16 + l16) * 128 + ((lc ^ (l16 & 7)) * 8));
            #pragma unroll
            for (int v = 0; v < 3; ++v)
                #pragma unroll
                for (int i = 0; i < 4; ++i)
                    facc[v][i] = __builtin_amdgcn_mfma_f32_16x16x32_f16(
                        ah[i], bh[v], facc[v][i], 0, 0, 0);
            __syncthreads();
        }
        #pragma unroll
        for (int i = 0; i < 4; ++i) {
            int o = wm * 64 + i * 16 + quad * 4;
            #pragma unroll
            for (int v = 0; v < 3; ++v) stsw256(HdL, v, l16, o, facc[v][i]);
        }
    }

    // S0: a0 = vnrelu(hidden, Wd0*hidden(+addD0))
    {
        constexpr int C = FIRST ? 256 : 128;
        f4_t acc[3][4];
        #pragma unroll
        for (int v = 0; v < 3; ++v)
            #pragma unroll
            for (int i = 0; i < 4; ++i)
                #pragma unroll
                for (int e = 0; e < 4; ++e) acc[v][i][e] = 0.f;

        for (int k0 = 0; k0 < C; k0 += 32) {
            #pragma unroll
            for (int c = t; c < 1024; c += 256) {
                int row = c >> 2, ch = c & 3;
                size_t g = (size_t)row * 256 + k0 + ch * 8;
                *(uint4*)(AsA + row * 32 + ((ch ^ (row & 3)) * 8)) =
                    *(const uint4*)(Wd0 + g);
            }
            __syncthreads();
            h8_t ah[4], bh[3];
            #pragma unroll
            for (int i = 0; i < 4; ++i)
                ah[i] = *(const h8_t*)(AsA + (wm * 64 + i * 16 + l16) * 32 + sw);
            int lc = (k0 >> 3) + quad;
            if (FIRST) {
                #pragma unroll
                for (int v = 0; v < 3; ++v)
                    bh[v] = *(const h8_t*)(HdL + (v * 16 + l16) * 256 + ((lc ^ (l16 & 7)) * 8));
            } else {
                #pragma unroll
                for (int v = 0; v < 3; ++v)
                    bh[v] = *(const h8_t*)(hL + (v * 16 + l16) * 128 + ((lc ^ (l16 & 7)) * 8));
            }
            #pragma unroll
            for (int v = 0; v < 3; ++v)
                #pragma unroll
                for (int i = 0; i < 4; ++i)
                    acc[v][i] = __builtin_amdgcn_mfma_f32_16x16x32_f16(
                        ah[i], bh[v], acc[v][i], 0, 0, 0);
            __syncthreads();
        }
        #pragma unroll
        for (int i = 0; i < 4; ++i) {
            int o = wm * 64 + i * 16 + quad * 4;
            f4_t d[3], p[3];
            #pragma unroll
            for (int v = 0; v < 3; ++v) {
                d[v] = acc[v][i];
                if (!FIRST) {
                    float4 ra = *(const float4*)(addD0 + (size_t)(b * 3 + v) * 256 + o);
                    d[v][0] += ra.x; d[v][1] += ra.y; d[v][2] += ra.z; d[v][3] += ra.w;
                }
            }
            if (FIRST) {
                #pragma unroll
                for (int v = 0; v < 3; ++v)
                    p[v] = ldsw256(HdL, v, l16, o);
            } else {
                if (o < 128) {
                    #pragma unroll
                    for (int v = 0; v < 3; ++v)
                        p[v] = ldsw128(hL, v, l16, o);
                } else {
                    #pragma unroll
                    for (int e = 0; e < 4; ++e) {
                        const float* Pc = P + (size_t)(b * 128 + o - 128 + e) * 3;
                        p[0][e] = Pc[0]; p[1][e] = Pc[1]; p[2][e] = Pc[2];
                    }
                }
            }
            f4_t q[3];
            #pragma unroll
            for (int e = 0; e < 4; ++e) {
                float dot = p[0][e] * d[0][e] + p[1][e] * d[1][e] + p[2][e] * d[2][e];
                float dsq = d[0][e] * d[0][e] + d[1][e] * d[1][e] + d[2][e] * d[2][e] + EPS_;
                float cf = dot / dsq;
                if (dot >= 0.f) { q[0][e] = p[0][e]; q[1][e] = p[1][e]; q[2][e] = p[2][e]; }
                else {
                    q[0][e] = p[0][e] - cf * d[0][e];
                    q[1][e] = p[1][e] - cf * d[1][e];
                    q[2][e] = p[2][e] - cf * d[2][e];
                }
            }
            #pragma unroll
            for (int v = 0; v < 3; ++v) stsw256(a0L, v, l16, o, q[v]);
        }
    }

    // S1: net = W0 * a0
    f4_t acc[3][2];
    #pragma unroll
    for (int v = 0; v < 3; ++v)
        #pragma unroll
        for (int i = 0; i < 2; ++i)
            #pragma unroll
            for (int e = 0; e < 4; ++e) acc[v][i][e] = 0.f;

    for (int k0 = 0; k0 < 256; k0 += 32) {
        #pragma unroll
        for (int c = t; c < 512; c += 256) {
            int row = c >> 2, ch = c & 3;
            size_t g = (size_t)row * 256 + k0 + ch * 8;
            *(uint4*)(AsA + row * 32 + ((ch ^ (row & 3)) * 8)) = *(const uint4*)(W0 + g);
        }
        __syncthreads();
        h8_t ah[2], bh[3];
        #pragma unroll
        for (int i = 0; i < 2; ++i)
            ah[i] = *(const h8_t*)(AsA + (wm * 32 + i * 16 + l16) * 32 + sw);
        int lc = (k0 >> 3) + quad;
        #pragma unroll
        for (int v = 0; v < 3; ++v)
            bh[v] = *(const h8_t*)(a0L + (v * 16 + l16) * 256 + ((lc ^ (l16 & 7)) * 8));
        #pragma unroll
        for (int v = 0; v < 3; ++v)
            #pragma unroll
            for (int i = 0; i < 2; ++i)
                acc[v][i] = __builtin_amdgcn_mfma_f32_16x16x32_f16(
                    ah[i], bh[v], acc[v][i], 0, 0, 0);
        __syncthreads();
    }
    #pragma unroll
    for (int i = 0; i < 2; ++i) {
        int o = wm * 32 + i * 16 + quad * 4;
        #pragma unroll
        for (int v = 0; v < 3; ++v) stsw128(netL, v, l16, o, acc[v][i]);
    }

    // S2: a1 = vnrelu(net, Wd1*net)
    #pragma unroll
    for (int v = 0; v < 3; ++v)
        #pragma unroll
        for (int i = 0; i < 2; ++i)
            #pragma unroll
            for (int e = 0; e < 4; ++e) acc[v][i][e] = 0.f;

    for (int k0 = 0; k0 < 128; k0 += 32) {
        #pragma unroll
        for (int c = t; c < 512; c += 256) {
            int row = c >> 2, ch = c & 3;
            size_t g = (size_t)row * 128 + k0 + ch * 8;
            *(uint4*)(AsB + row * 32 + ((ch ^ (row & 3)) * 8)) = *(const uint4*)(Wd1 + g);
        }
        __syncthreads();
        h8_t ah[2], bh[3];
        #pragma unroll
        for (int i = 0; i < 2; ++i)
            ah[i] = *(const h8_t*)(AsB + (wm * 32 + i * 16 + l16) * 32 + sw);
        int lc = (k0 >> 3) + quad;
        #pragma unroll
        for (int v = 0; v < 3; ++v)
            bh[v] = *(const h8_t*)(netL + (v * 16 + l16) * 128 + ((lc ^ (l16 & 7)) * 8));
        #pragma unroll
        for (int v = 0; v < 3; ++v)
            #pragma unroll
            for (int i = 0; i < 2; ++i)
                acc[v][i] = __builtin_amdgcn_mfma_f32_16x16x32_f16(
                    ah[i], bh[v], acc[v][i], 0, 0, 0);
        __syncthreads();
    }
    #pragma unroll
    for (int i = 0; i < 2; ++i) {
        int o = wm * 32 + i * 16 + quad * 4;
        f4_t p[3], q[3];
        #pragma unroll
        for (int v = 0; v < 3; ++v) p[v] = ldsw128(netL, v, l16, o);
        #pragma unroll
        for (int e = 0; e < 4; ++e) {
            float dot = p[0][e] * acc[0][i][e] + p[1][e] * acc[1][i][e] + p[2][e] * acc[2][i][e];
            float dsq = acc[0][i][e] * acc[0][i][e] + acc[1][i][e] * acc[1][i][e]
                      + acc[2][i][e] * acc[2][i][e] + EPS_;
            float cf = dot / dsq;
            if (dot >= 0.f) { q[0][e] = p[0][e]; q[1][e] = p[1][e]; q[2][e] = p[2][e]; }
            else {
                q[0][e] = p[0][e] - cf * acc[0][i][e];
                q[1][e] = p[1][e] - cf * acc[1][i][e];
                q[2][e] = p[2][e] - cf * acc[2][i][e];
            }
        }
        #pragma unroll
        for (int v = 0; v < 3; ++v) stsw128(a1L, v, l16, o, q[v]);
    }
    __syncthreads();

    // S3: h = Ws*hidden + W1*a1 (+addWs)
    #pragma unroll
    for (int v = 0; v < 3; ++v)
        #pragma unroll
        for (int i = 0; i < 2; ++i)
            #pragma unroll
            for (int e = 0; e < 4; ++e) acc[v][i][e] = 0.f;

    {
        constexpr int C0 = FIRST ? 256 : 128;
        for (int k0 = 0; k0 < C0; k0 += 32) {
            #pragma unroll
            for (int c = t; c < 512; c += 256) {
                int row = c >> 2, ch = c & 3;
                size_t g = (size_t)row * 256 + k0 + ch * 8;
                *(uint4*)(AsB + row * 32 + ((ch ^ (row & 3)) * 8)) = *(const uint4*)(Ws + g);
            }
            __syncthreads();
            h8_t ah[2], bh[3];
            #pragma unroll
            for (int i = 0; i < 2; ++i)
                ah[i] = *(const h8_t*)(AsB + (wm * 32 + i * 16 + l16) * 32 + sw);
            int lc = (k0 >> 3) + quad;
            if (FIRST) {
                #pragma unroll
                for (int v = 0; v < 3; ++v)
                    bh[v] = *(const h8_t*)(HdL + (v * 16 + l16) * 256 + ((lc ^ (l16 & 7)) * 8));
            } else {
                #pragma unroll
                for (int v = 0; v < 3; ++v)
                    bh[v] = *(const h8_t*)(hL + (v * 16 + l16) * 128 + ((lc ^ (l16 & 7)) * 8));
            }
            #pragma unroll
            for (int v = 0; v < 3; ++v)
                #pragma unroll
                for (int i = 0; i < 2; ++i)
                    acc[v][i] = __builtin_amdgcn_mfma_f32_16x16x32_f16(
                        ah[i], bh[v], acc[v][i], 0, 0, 0);
            __syncthreads();
        }
        for (int k0 = 0; k0 < 128; k0 += 32) {
            #pragma unroll
            for (int c = t; c < 512; c += 256) {
                int row = c >> 2, ch = c & 3;
                size_t g = (size_t)row * 128 + k0 + ch * 8;
                *(uint4*)(AsB + row * 32 + ((ch ^ (row & 3)) * 8)) = *(const uint4*)(W1 + g);
            }
            __syncthreads();
            h8_t ah[2], bh[3];
            #pragma unroll
            for (int i = 0; i < 2; ++i)
                ah[i] = *(const h8_t*)(AsB + (wm * 32 + i * 16 + l16) * 32 + sw);
            int lc = (k0 >> 3) + quad;
            #pragma unroll
            for (int v = 0; v < 3; ++v)
                bh[v] = *(const h8_t*)(a1L + (v * 16 + l16) * 128 + ((lc ^ (l16 & 7)) * 8));
            #pragma unroll
            for (int v = 0; v < 3; ++v)
                #pragma unroll
                for (int i = 0; i < 2; ++i)
                    acc[v][i] = __builtin_amdgcn_mfma_f32_16x16x32_f16(
                        ah[i], bh[v], acc[v][i], 0, 0, 0);
            __syncthreads();
        }
    }

    const size_t slot = (size_t)b * 64 + nt;
    #pragma unroll
    for (int i = 0; i < 2; ++i) {
        int o = wm * 32 + i * 16 + quad * 4;
        f4_t d[3];
        #pragma unroll
        for (int v = 0; v < 3; ++v) {
            d[v] = acc[v][i];
            if (!FIRST) {
                float4 ra = *(const float4*)(addWs + (size_t)(b * 3 + v) * 128 + o);
                d[v][0] += ra.x; d[v][1] += ra.y; d[v][2] += ra.z; d[v][3] += ra.w;
            }
            if (WRITE_OUT)
                st4h(outH, (row0 + (size_t)v * N_) * 128 + o, d[v]);
        }
        #pragma unroll
        for (int v = 0; v < 3; ++v)
            #pragma unroll
            for (int e = 0; e < 4; ++e) {
                float s = d[v][e];
                s += __shfl_xor(s, 1);
                s += __shfl_xor(s, 2);
                s += __shfl_xor(s, 4);
                s += __shfl_xor(s, 8);
                d[v][e] = s;
            }
        if (l16 == 0) {
            #pragma unroll
            for (int v = 0; v < 3; ++v)
                #pragma unroll
                for (int e = 0; e < 4; ++e)
                    Pp[slot * 384 + (size_t)(o + e) * 3 + v] = d[v][e];
        }
    }
}

// ---------------------------------------------------------------------------
// Pool stage 2 + rowadd for the NEXT block (intermediate blocks).
// ---------------------------------------------------------------------------
__global__ __launch_bounds__(256) void pool_rowadd(const float* __restrict__ Pp,
                                                   const float* __restrict__ Wd0n,
                                                   const float* __restrict__ Wsn,
                                                   float* __restrict__ P,
                                                   float* __restrict__ addD0,
                                                   float* __restrict__ addWs) {
    int s = blockIdx.x;
    int b = s / 3, v = s % 3;
    int t = threadIdx.x;
    __shared__ float Pl[128];
    if (t < 128) {
        float sum = 0.f;
        const float* p = Pp + (size_t)b * 64 * 384 + (size_t)t * 3 + v;
        #pragma unroll 4
        for (int sl = 0; sl < 64; ++sl) sum += p[(size_t)sl * 384];
        sum *= (1.0f / (float)N_);
        Pl[t] = sum;
        P[(size_t)(b * 128 + t) * 3 + v] = sum;
    }
    __syncthreads();
    float sum = 0.f;
    const float* wr = Wd0n + (size_t)t * 256 + 128;
    #pragma unroll 8
    for (int c = 0; c < 128; ++c) sum += wr[c] * Pl[c];
    addD0[(size_t)s * 256 + t] = sum;
    if (t < 128) {
        const float* wr2 = Wsn + (size_t)t * 256 + 128;
        float s2 = 0.f;
        #pragma unroll 8
        for (int c = 0; c < 128; ++c) s2 += wr2[c] * Pl[c];
        addWs[(size_t)s * 128 + t] = s2;
    }
}

// ---------------------------------------------------------------------------
// Final pool + final stage fused: per-b block pools all 3 v into LDS, then
// applies vn_lrelu(P, Wd*P, 0.2) and Wc (fp32, identical math to reference).
// ---------------------------------------------------------------------------
__global__ __launch_bounds__(128) void pool_final(const float* __restrict__ Pp,
                                                  const float* __restrict__ Wd,
                                                  const float* __restrict__ Wc,
                                                  float* __restrict__ out) {
    int b = blockIdx.x;
    int t = threadIdx.x;
    __shared__ float hid[H_][3];
    __shared__ float act[H_][3];
    {
        float s0 = 0.f, s1 = 0.f, s2 = 0.f;
        const float* p = Pp + (size_t)b * 64 * 384 + (size_t)t * 3;
        #pragma unroll 4
        for (int sl = 0; sl < 64; ++sl) {
            const float* q = p + (size_t)sl * 384;
            s0 += q[0]; s1 += q[1]; s2 += q[2];
        }
        const float inv = 1.0f / (float)N_;
        hid[t][0] = s0 * inv; hid[t][1] = s1 * inv; hid[t][2] = s2 * inv;
    }
    __syncthreads();

    float d0 = 0.f, d1 = 0.f, d2 = 0.f;
    const float* wd = Wd + (size_t)t * H_;
    for (int c = 0; c < H_; ++c) {
        float w = wd[c];
        d0 += w * hid[c][0]; d1 += w * hid[c][1]; d2 += w * hid[c][2];
    }
    float p0 = hid[t][0], p1 = hid[t][1], p2 = hid[t][2];
    float dot = p0 * d0 + p1 * d1 + p2 * d2;
    float dsq = d0 * d0 + d1 * d1 + d2 * d2 + EPS_;
    float cf = dot / dsq;
    float q0, q1, q2;
    if (dot >= 0.f) { q0 = p0; q1 = p1; q2 = p2; }
    else            { q0 = p0 - cf * d0; q1 = p1 - cf * d1; q2 = p2 - cf * d2; }
    act[t][0] = 0.2f * p0 + 0.8f * q0;
    act[t][1] = 0.2f * p1 + 0.8f * q1;
    act[t][2] = 0.2f * p2 + 0.8f * q2;
    __syncthreads();

    float o0 = 0.f, o1 = 0.f, o2 = 0.f;
    const float* wc = Wc + (size_t)t * H_;
    for (int c = 0; c < H_; ++c) {
        float w = wc[c];
        o0 += w * act[c][0]; o1 += w * act[c][1]; o2 += w * act[c][2];
    }
    size_t ob = ((size_t)b * H_ + t) * 3;
    out[ob + 0] = o0; out[ob + 1] = o1; out[ob + 2] = o2;
}

// ---------------------------------------------------------------------------
extern "C" void kernel_launch(void* const* d_in, const int* in_sizes, int n_in,
                              void* d_out, int out_size, void* d_ws, size_t ws_size,
                              hipStream_t stream) {
    const float* x   = (const float*)d_in[0];
    const float* Wf  = (const float*)d_in[1];
    const float* Wdp = (const float*)d_in[2];
    const float* Wfc = (const float*)d_in[3];
    const float* Wd0 = (const float*)d_in[4];
    const float* W0  = (const float*)d_in[5];
    const float* Wd1 = (const float*)d_in[6];
    const float* W1  = (const float*)d_in[7];
    const float* Wsc = (const float*)d_in[8];
    const float* Wda = (const float*)d_in[9];
    const float* Wc  = (const float*)d_in[10];
    float* out = (float*)d_out;
    (void)in_sizes; (void)n_in; (void)out_size; (void)ws_size;

    char* ws = (char*)d_ws;
    size_t off = 0;
    auto alloc = [&](size_t bytes) {
        void* p = ws + off;
        off = (off + bytes + 255) & ~(size_t)255;
        return p;
    };
    const size_t e128 = (size_t)R_ * 128;
    half_t* wAll  = (half_t*)alloc((size_t)W_TOT * 2);
    half_t* h1F   = (half_t*)alloc(e128 * 2);
    half_t* hF[2] = { (half_t*)alloc(e128 * 2), (half_t*)alloc(e128 * 2) };
    float*  addD0 = (float*) alloc(24 * 256 * 4);
    float*  addWs = (float*) alloc(24 * 128 * 4);
    float*  Pp    = (float*) alloc((size_t)B_ * 64 * 384 * 4);
    float*  P     = (float*) alloc((size_t)B_ * 128 * 3 * 4);

    const half_t* whFc = wAll + OFF_FC;
    const half_t* whD0 = wAll + OFF_D0;
    const half_t* whW0 = wAll + OFF_W0;
    const half_t* whD1 = wAll + OFF_D1;
    const half_t* whW1 = wAll + OFF_W1;
    const half_t* whWs = wAll + OFF_WS;

    hipLaunchKernelGGL(knn_conv, dim3(B_ * N_ / 4), dim3(256), 0, stream,
                       x, Wf, Wdp, Wfc, Wd0, W0, Wd1, W1, Wsc, wAll, h1F);

    for (int i = 0; i < 4; ++i) {
        int cur = i & 1, prv = cur ^ 1;
        if (i == 0) {
            block_full<true, true><<<dim3(64, 1, 8), 256, 0, stream>>>(
                whFc, whD0, whW0, whD1, whWs, whW1,
                h1F, nullptr, nullptr, nullptr, hF[cur], Pp);
        } else if (i < 3) {
            block_full<false, true><<<dim3(64, 1, 8), 256, 0, stream>>>(
                whFc, whD0 + (size_t)i * 65536, whW0 + (size_t)i * 32768,
                whD1 + (size_t)i * 16384, whWs + (size_t)i * 32768,
                whW1 + (size_t)i * 16384,
                hF[prv], P, addD0, addWs, hF[cur], Pp);
        } else {
            block_full<false, false><<<dim3(64, 1, 8), 256, 0, stream>>>(
                whFc, whD0 + (size_t)i * 65536, whW0 + (size_t)i * 32768,
                whD1 + (size_t)i * 16384, whWs + (size_t)i * 32768,
                whW1 + (size_t)i * 16384,
                hF[prv], P, addD0, addWs, nullptr, Pp);
        }
        if (i < 3) {
            hipLaunchKernelGGL(pool_rowadd, dim3(24), dim3(256), 0, stream,
                               Pp, Wd0 + (size_t)(i + 1) * 65536,
                               Wsc + (size_t)(i + 1) * 32768, P, addD0, addWs);
        } else {
            hipLaunchKernelGGL(pool_final, dim3(B_), dim3(128), 0, stream,
                               Pp, Wda, Wc, out);
        }
    }
}

// Round 16
// 279.675 us; speedup vs baseline: 1.1972x; 1.1972x over previous
//
#include <hip/hip_runtime.h>
#include <cfloat>
#include <cstdint>

#define B_   8
#define N_   1024
#define H_   128
#define K_   20
#define EPS_ 1e-6f
#define R_   (B_ * 3 * N_)

typedef _Float16 half_t;
typedef _Float16 h8_t __attribute__((ext_vector_type(8)));
typedef _Float16 h4_t __attribute__((ext_vector_type(4)));
typedef __attribute__((ext_vector_type(4))) float f4_t;

__device__ inline void st4h(half_t* __restrict__ p, size_t off, f4_t v) {
    h4_t o;
    o[0] = (half_t)v[0]; o[1] = (half_t)v[1]; o[2] = (half_t)v[2]; o[3] = (half_t)v[3];
    *(h4_t*)(p + off) = o;
}

// ---------------------------------------------------------------------------
// All-weights fp32 -> fp16 (separate kernel: keeps knn_conv VGPR budget low).
// ---------------------------------------------------------------------------
#define OFF_FC 0
#define OFF_D0 32768
#define OFF_W0 294912
#define OFF_D1 425984
#define OFF_W1 491520
#define OFF_WS 557056
#define W_TOT  688128
__global__ __launch_bounds__(256) void cvt_all(const float* __restrict__ Wfc,
                                               const float* __restrict__ Wd0,
                                               const float* __restrict__ W0,
                                               const float* __restrict__ Wd1,
                                               const float* __restrict__ W1,
                                               const float* __restrict__ Wsc,
                                               half_t* __restrict__ w) {
    int i = blockIdx.x * 256 + threadIdx.x;
    if (i >= W_TOT) return;
    const float* src; int off;
    if (i < OFF_W0)      { if (i < OFF_D0) { src = Wfc; off = OFF_FC; }
                           else            { src = Wd0; off = OFF_D0; } }
    else if (i < OFF_W1) { if (i < OFF_D1) { src = W0;  off = OFF_W0; }
                           else            { src = Wd1; off = OFF_D1; } }
    else                 { if (i < OFF_WS) { src = W1;  off = OFF_W1; }
                           else            { src = Wsc; off = OFF_WS; } }
    w[i] = (half_t)src[i - off];
}

// ---------------------------------------------------------------------------
// Fused kNN + conv_pos (R14-proven structure, 36 VGPR): LDS point cloud,
// per-wave u32 butterfly selection, direct conv for 2 channels/lane.
// Only delta vs R14: cf uses v_rcp_f32 (validated in R15, absmax ok).
// ---------------------------------------------------------------------------
__global__ __launch_bounds__(256) void knn_conv(const float* __restrict__ x,
                                                const float* __restrict__ Wf,
                                                const float* __restrict__ Wd,
                                                half_t* __restrict__ h1) {
    __shared__ float xs[N_], ys[N_], zs[N_];
    __shared__ int opw[4][K_];
    int t = threadIdx.x;
    int wv = t >> 6, lane = t & 63;
    int b = blockIdx.x >> 8;
    int n = (blockIdx.x & 255) * 4 + wv;
    const float* xb = x + (size_t)b * N_ * 3;
    for (int j = t; j < N_; j += 256) {
        xs[j] = xb[j * 3 + 0];
        ys[j] = xb[j * 3 + 1];
        zs[j] = xb[j * 3 + 2];
    }
    __syncthreads();

    float cx = xs[n], cy = ys[n], cz = zs[n];
    uint ku[16];
    #pragma unroll
    for (int k = 0; k < 16; ++k) {
        int j = lane + (k << 6);
        float dx = xs[j] - cx, dy = ys[j] - cy, dz = zs[j] - cz;
        float d = dx * dx + dy * dy + dz * dz;
        ku[k] = (__float_as_uint(d) & 0xFFFFFC00u) | (uint)j;
    }
    for (int s = 0; s < K_; ++s) {
        uint m = ku[0];
        #pragma unroll
        for (int k = 1; k < 16; ++k) m = min(m, ku[k]);
        #pragma unroll
        for (int o = 32; o; o >>= 1) m = min(m, (uint)__shfl_xor((int)m, o));
        int j = (int)(m & 1023u);
        if ((j & 63) == lane) {
            opw[wv][s] = j;
            ku[j >> 6] = 0xFFFFFFFFu;
        }
    }
    __syncthreads();

    // conv for channels lane and lane+64
    float wf[2][3], wd[2][3];
    #pragma unroll
    for (int c = 0; c < 2; ++c) {
        int ch = lane + c * 64;
        wf[c][0] = Wf[ch * 3 + 0]; wf[c][1] = Wf[ch * 3 + 1]; wf[c][2] = Wf[ch * 3 + 2];
        wd[c][0] = Wd[ch * 3 + 0]; wd[c][1] = Wd[ch * 3 + 1]; wd[c][2] = Wd[ch * 3 + 2];
    }
    float ax[2] = {0.f, 0.f}, ay[2] = {0.f, 0.f}, az[2] = {0.f, 0.f};
    for (int k = 0; k < K_; ++k) {
        int j = opw[wv][k];
        float nx = xs[j], ny = ys[j], nz = zs[j];
        float ex = nx - cx, ey = ny - cy, ez = nz - cz;
        float rx = ny * cz - nz * cy;
        float ry = nz * cx - nx * cz;
        float rz = nx * cy - ny * cx;
        #pragma unroll
        for (int c = 0; c < 2; ++c) {
            float fx = wf[c][0] * ex + wf[c][1] * cx + wf[c][2] * rx;
            float fy = wf[c][0] * ey + wf[c][1] * cy + wf[c][2] * ry;
            float fz = wf[c][0] * ez + wf[c][1] * cz + wf[c][2] * rz;
            float gx = wd[c][0] * ex + wd[c][1] * cx + wd[c][2] * rx;
            float gy = wd[c][0] * ey + wd[c][1] * cy + wd[c][2] * ry;
            float gz = wd[c][0] * ez + wd[c][1] * cz + wd[c][2] * rz;
            float dot = fx * gx + fy * gy + fz * gz;
            float dsq = gx * gx + gy * gy + gz * gz + EPS_;
            float cf = dot * __builtin_amdgcn_rcpf(dsq);
            float qx, qy, qz;
            if (dot >= 0.f) { qx = fx; qy = fy; qz = fz; }
            else            { qx = fx - cf * gx; qy = fy - cf * gy; qz = fz - cf * gz; }
            ax[c] += 0.2f * fx + 0.8f * qx;
            ay[c] += 0.2f * fy + 0.8f * qy;
            az[c] += 0.2f * fz + 0.8f * qz;
        }
    }
    const float inv = 1.0f / (float)K_;
    size_t r0 = ((size_t)b * 3) * N_ + n;
    #pragma unroll
    for (int c = 0; c < 2; ++c) {
        int ch = lane + c * 64;
        h1[(r0) * H_ + ch]          = (half_t)(ax[c] * inv);
        h1[(r0 + N_) * H_ + ch]     = (half_t)(ay[c] * inv);
        h1[(r0 + 2 * N_) * H_ + ch] = (half_t)(az[c] * inv);
    }
}

// ---------------------------------------------------------------------------
// Swizzled LDS helpers (128/256-ch row buffers).
// ---------------------------------------------------------------------------
__device__ inline void stsw128(half_t* __restrict__ buf, int v, int n, int o, f4_t val) {
    int phys = (((o >> 3) ^ (n & 7)) * 8) + (o & 7);
    half_t* p = buf + (v * 16 + n) * 128 + phys;
    h4_t h;
    h[0] = (half_t)val[0]; h[1] = (half_t)val[1];
    h[2] = (half_t)val[2]; h[3] = (half_t)val[3];
    *(h4_t*)p = h;
}
__device__ inline f4_t ldsw128(const half_t* __restrict__ buf, int v, int n, int o) {
    int phys = (((o >> 3) ^ (n & 7)) * 8) + (o & 7);
    const half_t* p = buf + (v * 16 + n) * 128 + phys;
    h4_t x = *(const h4_t*)p;
    f4_t r;
    r[0] = (float)x[0]; r[1] = (float)x[1]; r[2] = (float)x[2]; r[3] = (float)x[3];
    return r;
}
__device__ inline void stsw256(half_t* __restrict__ buf, int v, int n, int o, f4_t val) {
    int phys = (((o >> 3) ^ (n & 7)) * 8) + (o & 7);
    half_t* p = buf + (v * 16 + n) * 256 + phys;
    h4_t h;
    h[0] = (half_t)val[0]; h[1] = (half_t)val[1];
    h[2] = (half_t)val[2]; h[3] = (half_t)val[3];
    *(h4_t*)p = h;
}
__device__ inline f4_t ldsw256(const half_t* __restrict__ buf, int v, int n, int o) {
    int phys = (((o >> 3) ^ (n & 7)) * 8) + (o & 7);
    const half_t* p = buf + (v * 16 + n) * 256 + phys;
    h4_t x = *(const h4_t*)p;
    f4_t r;
    r[0] = (float)x[0]; r[1] = (float)x[1]; r[2] = (float)x[2]; r[3] = (float)x[3];
    return r;
}

// ---------------------------------------------------------------------------
// block_full: entire resnet block per (n-tile 16, b) block (R13/R14 design).
// ---------------------------------------------------------------------------
template<bool FIRST, bool WRITE_OUT>
__global__ __launch_bounds__(256) void block_full(const half_t* __restrict__ Wfc,
                                                  const half_t* __restrict__ Wd0,
                                                  const half_t* __restrict__ W0,
                                                  const half_t* __restrict__ Wd1,
                                                  const half_t* __restrict__ Ws,
                                                  const half_t* __restrict__ W1,
                                                  const half_t* __restrict__ hprev,
                                                  const float* __restrict__ P,
                                                  const float* __restrict__ addD0,
                                                  const float* __restrict__ addWs,
                                                  half_t* __restrict__ outH,
                                                  float* __restrict__ Pp) {
    __shared__ __align__(16) char smem[FIRST ? 77824 : 53248];
    half_t* hL   = (half_t*)(smem);
    half_t* netL = (half_t*)(FIRST ? smem : smem + 36864);
    half_t* HdL  = (half_t*)(smem + 12288);
    half_t* a0L  = (half_t*)(FIRST ? smem + 36864 : smem + 12288);
    half_t* a1L  = (half_t*)(FIRST ? smem + 36864 : smem + 24576);
    half_t* AsA  = (half_t*)(FIRST ? smem + 61440 : smem + 36864);
    half_t* AsB  = (half_t*)(FIRST ? smem + 61440 : smem + 12288);

    const int t = threadIdx.x;
    const int lane = t & 63, wm = t >> 6;
    const int l16 = lane & 15, quad = lane >> 4;
    const int sw = (quad ^ (l16 & 3)) * 8;
    const int b  = blockIdx.z;
    const int nt = blockIdx.x;
    const int n0 = nt * 16;
    const size_t row0 = (size_t)(b * 3) * N_ + (n0 + l16);

    #pragma unroll
    for (int c = t; c < 768; c += 256) {
        int v = c >> 8, rem = c & 255;
        int n = rem >> 4, ch = rem & 15;
        size_t g = (size_t)((b * 3 + v) * N_ + n0 + n) * 128 + ch * 8;
        *(uint4*)(hL + (v * 16 + n) * 128 + ((ch ^ (n & 7)) * 8)) =
            *(const uint4*)(hprev + g);
    }

    if (FIRST) {
        f4_t facc[3][4];
        #pragma unroll
        for (int v = 0; v < 3; ++v)
            #pragma unroll
            for (int i = 0; i < 4; ++i)
                #pragma unroll
                for (int e = 0; e < 4; ++e) facc[v][i][e] = 0.f;
        for (int k0 = 0; k0 < 128; k0 += 32) {
            #pragma unroll
            for (int c = t; c < 1024; c += 256) {
                int row = c >> 2, ch = c & 3;
                size_t g = (size_t)row * 128 + k0 + ch * 8;
                *(uint4*)(AsA + row * 32 + ((ch ^ (row & 3)) * 8)) =
                    *(const uint4*)(Wfc + g);
            }
            __syncthreads();
            h8_t ah[4], bh[3];
            #pragma unroll
            for (int i = 0; i < 4; ++i)
                ah[i] = *(const h8_t*)(AsA + (wm * 64 + i * 16 + l16) * 32 + sw);
            int lc = (k0 >> 3) + quad;
            #pragma unroll
            for (int v = 0; v < 3; ++v)
                bh[v] = *(const h8_t*)(hL + (v * 16 + l16) * 128 + ((lc ^ (l16 & 7)) * 8));
            #pragma unroll
            for (int v = 0; v < 3; ++v)
                #pragma unroll
                for (int i = 0; i < 4; ++i)
                    facc[v][i] = __builtin_amdgcn_mfma_f32_16x16x32_f16(
                        ah[i], bh[v], facc[v][i], 0, 0, 0);
            __syncthreads();
        }
        #pragma unroll
        for (int i = 0; i < 4; ++i) {
            int o = wm * 64 + i * 16 + quad * 4;
            #pragma unroll
            for (int v = 0; v < 3; ++v) stsw256(HdL, v, l16, o, facc[v][i]);
        }
    }

    // S0: a0 = vnrelu(hidden, Wd0*hidden(+addD0))
    {
        constexpr int C = FIRST ? 256 : 128;
        f4_t acc[3][4];
        #pragma unroll
        for (int v = 0; v < 3; ++v)
            #pragma unroll
            for (int i = 0; i < 4; ++i)
                #pragma unroll
                for (int e = 0; e < 4; ++e) acc[v][i][e] = 0.f;

        for (int k0 = 0; k0 < C; k0 += 32) {
            #pragma unroll
            for (int c = t; c < 1024; c += 256) {
                int row = c >> 2, ch = c & 3;
                size_t g = (size_t)row * 256 + k0 + ch * 8;
                *(uint4*)(AsA + row * 32 + ((ch ^ (row & 3)) * 8)) =
                    *(const uint4*)(Wd0 + g);
            }
            __syncthreads();
            h8_t ah[4], bh[3];
            #pragma unroll
            for (int i = 0; i < 4; ++i)
                ah[i] = *(const h8_t*)(AsA + (wm * 64 + i * 16 + l16) * 32 + sw);
            int lc = (k0 >> 3) + quad;
            if (FIRST) {
                #pragma unroll
                for (int v = 0; v < 3; ++v)
                    bh[v] = *(const h8_t*)(HdL + (v * 16 + l16) * 256 + ((lc ^ (l16 & 7)) * 8));
            } else {
                #pragma unroll
                for (int v = 0; v < 3; ++v)
                    bh[v] = *(const h8_t*)(hL + (v * 16 + l16) * 128 + ((lc ^ (l16 & 7)) * 8));
            }
            #pragma unroll
            for (int v = 0; v < 3; ++v)
                #pragma unroll
                for (int i = 0; i < 4; ++i)
                    acc[v][i] = __builtin_amdgcn_mfma_f32_16x16x32_f16(
                        ah[i], bh[v], acc[v][i], 0, 0, 0);
            __syncthreads();
        }
        #pragma unroll
        for (int i = 0; i < 4; ++i) {
            int o = wm * 64 + i * 16 + quad * 4;
            f4_t d[3], p[3];
            #pragma unroll
            for (int v = 0; v < 3; ++v) {
                d[v] = acc[v][i];
                if (!FIRST) {
                    float4 ra = *(const float4*)(addD0 + (size_t)(b * 3 + v) * 256 + o);
                    d[v][0] += ra.x; d[v][1] += ra.y; d[v][2] += ra.z; d[v][3] += ra.w;
                }
            }
            if (FIRST) {
                #pragma unroll
                for (int v = 0; v < 3; ++v)
                    p[v] = ldsw256(HdL, v, l16, o);
            } else {
                if (o < 128) {
                    #pragma unroll
                    for (int v = 0; v < 3; ++v)
                        p[v] = ldsw128(hL, v, l16, o);
                } else {
                    #pragma unroll
                    for (int e = 0; e < 4; ++e) {
                        const float* Pc = P + (size_t)(b * 128 + o - 128 + e) * 3;
                        p[0][e] = Pc[0]; p[1][e] = Pc[1]; p[2][e] = Pc[2];
                    }
                }
            }
            f4_t q[3];
            #pragma unroll
            for (int e = 0; e < 4; ++e) {
                float dot = p[0][e] * d[0][e] + p[1][e] * d[1][e] + p[2][e] * d[2][e];
                float dsq = d[0][e] * d[0][e] + d[1][e] * d[1][e] + d[2][e] * d[2][e] + EPS_;
                float cf = dot / dsq;
                if (dot >= 0.f) { q[0][e] = p[0][e]; q[1][e] = p[1][e]; q[2][e] = p[2][e]; }
                else {
                    q[0][e] = p[0][e] - cf * d[0][e];
                    q[1][e] = p[1][e] - cf * d[1][e];
                    q[2][e] = p[2][e] - cf * d[2][e];
                }
            }
            #pragma unroll
            for (int v = 0; v < 3; ++v) stsw256(a0L, v, l16, o, q[v]);
        }
    }

    // S1: net = W0 * a0
    f4_t acc[3][2];
    #pragma unroll
    for (int v = 0; v < 3; ++v)
        #pragma unroll
        for (int i = 0; i < 2; ++i)
            #pragma unroll
            for (int e = 0; e < 4; ++e) acc[v][i][e] = 0.f;

    for (int k0 = 0; k0 < 256; k0 += 32) {
        #pragma unroll
        for (int c = t; c < 512; c += 256) {
            int row = c >> 2, ch = c & 3;
            size_t g = (size_t)row * 256 + k0 + ch * 8;
            *(uint4*)(AsA + row * 32 + ((ch ^ (row & 3)) * 8)) = *(const uint4*)(W0 + g);
        }
        __syncthreads();
        h8_t ah[2], bh[3];
        #pragma unroll
        for (int i = 0; i < 2; ++i)
            ah[i] = *(const h8_t*)(AsA + (wm * 32 + i * 16 + l16) * 32 + sw);
        int lc = (k0 >> 3) + quad;
        #pragma unroll
        for (int v = 0; v < 3; ++v)
            bh[v] = *(const h8_t*)(a0L + (v * 16 + l16) * 256 + ((lc ^ (l16 & 7)) * 8));
        #pragma unroll
        for (int v = 0; v < 3; ++v)
            #pragma unroll
            for (int i = 0; i < 2; ++i)
                acc[v][i] = __builtin_amdgcn_mfma_f32_16x16x32_f16(
                    ah[i], bh[v], acc[v][i], 0, 0, 0);
        __syncthreads();
    }
    #pragma unroll
    for (int i = 0; i < 2; ++i) {
        int o = wm * 32 + i * 16 + quad * 4;
        #pragma unroll
        for (int v = 0; v < 3; ++v) stsw128(netL, v, l16, o, acc[v][i]);
    }

    // S2: a1 = vnrelu(net, Wd1*net)
    #pragma unroll
    for (int v = 0; v < 3; ++v)
        #pragma unroll
        for (int i = 0; i < 2; ++i)
            #pragma unroll
            for (int e = 0; e < 4; ++e) acc[v][i][e] = 0.f;

    for (int k0 = 0; k0 < 128; k0 += 32) {
        #pragma unroll
        for (int c = t; c < 512; c += 256) {
            int row = c >> 2, ch = c & 3;
            size_t g = (size_t)row * 128 + k0 + ch * 8;
            *(uint4*)(AsB + row * 32 + ((ch ^ (row & 3)) * 8)) = *(const uint4*)(Wd1 + g);
        }
        __syncthreads();
        h8_t ah[2], bh[3];
        #pragma unroll
        for (int i = 0; i < 2; ++i)
            ah[i] = *(const h8_t*)(AsB + (wm * 32 + i * 16 + l16) * 32 + sw);
        int lc = (k0 >> 3) + quad;
        #pragma unroll
        for (int v = 0; v < 3; ++v)
            bh[v] = *(const h8_t*)(netL + (v * 16 + l16) * 128 + ((lc ^ (l16 & 7)) * 8));
        #pragma unroll
        for (int v = 0; v < 3; ++v)
            #pragma unroll
            for (int i = 0; i < 2; ++i)
                acc[v][i] = __builtin_amdgcn_mfma_f32_16x16x32_f16(
                    ah[i], bh[v], acc[v][i], 0, 0, 0);
        __syncthreads();
    }
    #pragma unroll
    for (int i = 0; i < 2; ++i) {
        int o = wm * 32 + i * 16 + quad * 4;
        f4_t p[3], q[3];
        #pragma unroll
        for (int v = 0; v < 3; ++v) p[v] = ldsw128(netL, v, l16, o);
        #pragma unroll
        for (int e = 0; e < 4; ++e) {
            float dot = p[0][e] * acc[0][i][e] + p[1][e] * acc[1][i][e] + p[2][e] * acc[2][i][e];
            float dsq = acc[0][i][e] * acc[0][i][e] + acc[1][i][e] * acc[1][i][e]
                      + acc[2][i][e] * acc[2][i][e] + EPS_;
            float cf = dot / dsq;
            if (dot >= 0.f) { q[0][e] = p[0][e]; q[1][e] = p[1][e]; q[2][e] = p[2][e]; }
            else {
                q[0][e] = p[0][e] - cf * acc[0][i][e];
                q[1][e] = p[1][e] - cf * acc[1][i][e];
                q[2][e] = p[2][e] - cf * acc[2][i][e];
            }
        }
        #pragma unroll
        for (int v = 0; v < 3; ++v) stsw128(a1L, v, l16, o, q[v]);
    }
    __syncthreads();

    // S3: h = Ws*hidden + W1*a1 (+addWs)
    #pragma unroll
    for (int v = 0; v < 3; ++v)
        #pragma unroll
        for (int i = 0; i < 2; ++i)
            #pragma unroll
            for (int e = 0; e < 4; ++e) acc[v][i][e] = 0.f;

    {
        constexpr int C0 = FIRST ? 256 : 128;
        for (int k0 = 0; k0 < C0; k0 += 32) {
            #pragma unroll
            for (int c = t; c < 512; c += 256) {
                int row = c >> 2, ch = c & 3;
                size_t g = (size_t)row * 256 + k0 + ch * 8;
                *(uint4*)(AsB + row * 32 + ((ch ^ (row & 3)) * 8)) = *(const uint4*)(Ws + g);
            }
            __syncthreads();
            h8_t ah[2], bh[3];
            #pragma unroll
            for (int i = 0; i < 2; ++i)
                ah[i] = *(const h8_t*)(AsB + (wm * 32 + i * 16 + l16) * 32 + sw);
            int lc = (k0 >> 3) + quad;
            if (FIRST) {
                #pragma unroll
                for (int v = 0; v < 3; ++v)
                    bh[v] = *(const h8_t*)(HdL + (v * 16 + l16) * 256 + ((lc ^ (l16 & 7)) * 8));
            } else {
                #pragma unroll
                for (int v = 0; v < 3; ++v)
                    bh[v] = *(const h8_t*)(hL + (v * 16 + l16) * 128 + ((lc ^ (l16 & 7)) * 8));
            }
            #pragma unroll
            for (int v = 0; v < 3; ++v)
                #pragma unroll
                for (int i = 0; i < 2; ++i)
                    acc[v][i] = __builtin_amdgcn_mfma_f32_16x16x32_f16(
                        ah[i], bh[v], acc[v][i], 0, 0, 0);
            __syncthreads();
        }
        for (int k0 = 0; k0 < 128; k0 += 32) {
            #pragma unroll
            for (int c = t; c < 512; c += 256) {
                int row = c >> 2, ch = c & 3;
                size_t g = (size_t)row * 128 + k0 + ch * 8;
                *(uint4*)(AsB + row * 32 + ((ch ^ (row & 3)) * 8)) = *(const uint4*)(W1 + g);
            }
            __syncthreads();
            h8_t ah[2], bh[3];
            #pragma unroll
            for (int i = 0; i < 2; ++i)
                ah[i] = *(const h8_t*)(AsB + (wm * 32 + i * 16 + l16) * 32 + sw);
            int lc = (k0 >> 3) + quad;
            #pragma unroll
            for (int v = 0; v < 3; ++v)
                bh[v] = *(const h8_t*)(a1L + (v * 16 + l16) * 128 + ((lc ^ (l16 & 7)) * 8));
            #pragma unroll
            for (int v = 0; v < 3; ++v)
                #pragma unroll
                for (int i = 0; i < 2; ++i)
                    acc[v][i] = __builtin_amdgcn_mfma_f32_16x16x32_f16(
                        ah[i], bh[v], acc[v][i], 0, 0, 0);
            __syncthreads();
        }
    }

    const size_t slot = (size_t)b * 64 + nt;
    #pragma unroll
    for (int i = 0; i < 2; ++i) {
        int o = wm * 32 + i * 16 + quad * 4;
        f4_t d[3];
        #pragma unroll
        for (int v = 0; v < 3; ++v) {
            d[v] = acc[v][i];
            if (!FIRST) {
                float4 ra = *(const float4*)(addWs + (size_t)(b * 3 + v) * 128 + o);
                d[v][0] += ra.x; d[v][1] += ra.y; d[v][2] += ra.z; d[v][3] += ra.w;
            }
            if (WRITE_OUT)
                st4h(outH, (row0 + (size_t)v * N_) * 128 + o, d[v]);
        }
        #pragma unroll
        for (int v = 0; v < 3; ++v)
            #pragma unroll
            for (int e = 0; e < 4; ++e) {
                float s = d[v][e];
                s += __shfl_xor(s, 1);
                s += __shfl_xor(s, 2);
                s += __shfl_xor(s, 4);
                s += __shfl_xor(s, 8);
                d[v][e] = s;
            }
        if (l16 == 0) {
            #pragma unroll
            for (int v = 0; v < 3; ++v)
                #pragma unroll
                for (int e = 0; e < 4; ++e)
                    Pp[slot * 384 + (size_t)(o + e) * 3 + v] = d[v][e];
        }
    }
}

// ---------------------------------------------------------------------------
// Pool stage 2 + rowadd for the NEXT block (intermediate blocks).
// ---------------------------------------------------------------------------
__global__ __launch_bounds__(256) void pool_rowadd(const float* __restrict__ Pp,
                                                   const float* __restrict__ Wd0n,
                                                   const float* __restrict__ Wsn,
                                                   float* __restrict__ P,
                                                   float* __restrict__ addD0,
                                                   float* __restrict__ addWs) {
    int s = blockIdx.x;
    int b = s / 3, v = s % 3;
    int t = threadIdx.x;
    __shared__ float Pl[128];
    if (t < 128) {
        float sum = 0.f;
        const float* p = Pp + (size_t)b * 64 * 384 + (size_t)t * 3 + v;
        #pragma unroll 4
        for (int sl = 0; sl < 64; ++sl) sum += p[(size_t)sl * 384];
        sum *= (1.0f / (float)N_);
        Pl[t] = sum;
        P[(size_t)(b * 128 + t) * 3 + v] = sum;
    }
    __syncthreads();
    float sum = 0.f;
    const float* wr = Wd0n + (size_t)t * 256 + 128;
    #pragma unroll 8
    for (int c = 0; c < 128; ++c) sum += wr[c] * Pl[c];
    addD0[(size_t)s * 256 + t] = sum;
    if (t < 128) {
        const float* wr2 = Wsn + (size_t)t * 256 + 128;
        float s2 = 0.f;
        #pragma unroll 8
        for (int c = 0; c < 128; ++c) s2 += wr2[c] * Pl[c];
        addWs[(size_t)s * 128 + t] = s2;
    }
}

// ---------------------------------------------------------------------------
// Final pool + final stage fused (fp32, exact).
// ---------------------------------------------------------------------------
__global__ __launch_bounds__(128) void pool_final(const float* __restrict__ Pp,
                                                  const float* __restrict__ Wd,
                                                  const float* __restrict__ Wc,
                                                  float* __restrict__ out) {
    int b = blockIdx.x;
    int t = threadIdx.x;
    __shared__ float hid[H_][3];
    __shared__ float act[H_][3];
    {
        float s0 = 0.f, s1 = 0.f, s2 = 0.f;
        const float* p = Pp + (size_t)b * 64 * 384 + (size_t)t * 3;
        #pragma unroll 4
        for (int sl = 0; sl < 64; ++sl) {
            const float* q = p + (size_t)sl * 384;
            s0 += q[0]; s1 += q[1]; s2 += q[2];
        }
        const float inv = 1.0f / (float)N_;
        hid[t][0] = s0 * inv; hid[t][1] = s1 * inv; hid[t][2] = s2 * inv;
    }
    __syncthreads();

    float d0 = 0.f, d1 = 0.f, d2 = 0.f;
    const float* wd = Wd + (size_t)t * H_;
    for (int c = 0; c < H_; ++c) {
        float w = wd[c];
        d0 += w * hid[c][0]; d1 += w * hid[c][1]; d2 += w * hid[c][2];
    }
    float p0 = hid[t][0], p1 = hid[t][1], p2 = hid[t][2];
    float dot = p0 * d0 + p1 * d1 + p2 * d2;
    float dsq = d0 * d0 + d1 * d1 + d2 * d2 + EPS_;
    float cf = dot / dsq;
    float q0, q1, q2;
    if (dot >= 0.f) { q0 = p0; q1 = p1; q2 = p2; }
    else            { q0 = p0 - cf * d0; q1 = p1 - cf * d1; q2 = p2 - cf * d2; }
    act[t][0] = 0.2f * p0 + 0.8f * q0;
    act[t][1] = 0.2f * p1 + 0.8f * q1;
    act[t][2] = 0.2f * p2 + 0.8f * q2;
    __syncthreads();

    float o0 = 0.f, o1 = 0.f, o2 = 0.f;
    const float* wc = Wc + (size_t)t * H_;
    for (int c = 0; c < H_; ++c) {
        float w = wc[c];
        o0 += w * act[c][0]; o1 += w * act[c][1]; o2 += w * act[c][2];
    }
    size_t ob = ((size_t)b * H_ + t) * 3;
    out[ob + 0] = o0; out[ob + 1] = o1; out[ob + 2] = o2;
}

// ---------------------------------------------------------------------------
extern "C" void kernel_launch(void* const* d_in, const int* in_sizes, int n_in,
                              void* d_out, int out_size, void* d_ws, size_t ws_size,
                              hipStream_t stream) {
    const float* x   = (const float*)d_in[0];
    const float* Wf  = (const float*)d_in[1];
    const float* Wdp = (const float*)d_in[2];
    const float* Wfc = (const float*)d_in[3];
    const float* Wd0 = (const float*)d_in[4];
    const float* W0  = (const float*)d_in[5];
    const float* Wd1 = (const float*)d_in[6];
    const float* W1  = (const float*)d_in[7];
    const float* Wsc = (const float*)d_in[8];
    const float* Wda = (const float*)d_in[9];
    const float* Wc  = (const float*)d_in[10];
    float* out = (float*)d_out;
    (void)in_sizes; (void)n_in; (void)out_size; (void)ws_size;

    char* ws = (char*)d_ws;
    size_t off = 0;
    auto alloc = [&](size_t bytes) {
        void* p = ws + off;
        off = (off + bytes + 255) & ~(size_t)255;
        return p;
    };
    const size_t e128 = (size_t)R_ * 128;
    half_t* wAll  = (half_t*)alloc((size_t)W_TOT * 2);
    half_t* h1F   = (half_t*)alloc(e128 * 2);
    half_t* hF[2] = { (half_t*)alloc(e128 * 2), (half_t*)alloc(e128 * 2) };
    float*  addD0 = (float*) alloc(24 * 256 * 4);
    float*  addWs = (float*) alloc(24 * 128 * 4);
    float*  Pp    = (float*) alloc((size_t)B_ * 64 * 384 * 4);
    float*  P     = (float*) alloc((size_t)B_ * 128 * 3 * 4);

    const half_t* whFc = wAll + OFF_FC;
    const half_t* whD0 = wAll + OFF_D0;
    const half_t* whW0 = wAll + OFF_W0;
    const half_t* whD1 = wAll + OFF_D1;
    const half_t* whW1 = wAll + OFF_W1;
    const half_t* whWs = wAll + OFF_WS;

    hipLaunchKernelGGL(cvt_all, dim3((W_TOT + 255) / 256), dim3(256), 0, stream,
                       Wfc, Wd0, W0, Wd1, W1, Wsc, wAll);
    hipLaunchKernelGGL(knn_conv, dim3(B_ * N_ / 4), dim3(256), 0, stream,
                       x, Wf, Wdp, h1F);

    for (int i = 0; i < 4; ++i) {
        int cur = i & 1, prv = cur ^ 1;
        if (i == 0) {
            block_full<true, true><<<dim3(64, 1, 8), 256, 0, stream>>>(
                whFc, whD0, whW0, whD1, whWs, whW1,
                h1F, nullptr, nullptr, nullptr, hF[cur], Pp);
        } else if (i < 3) {
            block_full<false, true><<<dim3(64, 1, 8), 256, 0, stream>>>(
                whFc, whD0 + (size_t)i * 65536, whW0 + (size_t)i * 32768,
                whD1 + (size_t)i * 16384, whWs + (size_t)i * 32768,
                whW1 + (size_t)i * 16384,
                hF[prv], P, addD0, addWs, hF[cur], Pp);
        } else {
            block_full<false, false><<<dim3(64, 1, 8), 256, 0, stream>>>(
                whFc, whD0 + (size_t)i * 65536, whW0 + (size_t)i * 32768,
                whD1 + (size_t)i * 16384, whWs + (size_t)i * 32768,
                whW1 + (size_t)i * 16384,
                hF[prv], P, addD0, addWs, nullptr, Pp);
        }
        if (i < 3) {
            hipLaunchKernelGGL(pool_rowadd, dim3(24), dim3(256), 0, stream,
                               Pp, Wd0 + (size_t)(i + 1) * 65536,
                               Wsc + (size_t)(i + 1) * 32768, P, addD0, addWs);
        } else {
            hipLaunchKernelGGL(pool_final, dim3(B_), dim3(128), 0, stream,
                               Pp, Wda, Wc, out);
        }
    }
}